// Round 2
// baseline (2161.395 us; speedup 1.0000x reference)
//
#include <hip/hip_runtime.h>
#include <hip/hip_bf16.h>
#include <math.h>

using bf16 = __hip_bfloat16;
typedef __bf16 bf16x8v __attribute__((ext_vector_type(8)));
typedef float f32x4 __attribute__((ext_vector_type(4)));

__device__ __forceinline__ float b2f(bf16 x) { return __bfloat162float(x); }
__device__ __forceinline__ bf16 f2b(float x) { return __float2bfloat16(x); }

__device__ __forceinline__ void gload_lds16(const void* g, void* l) {
  __builtin_amdgcn_global_load_lds(
      (__attribute__((address_space(1))) void*)(void*)g,
      (__attribute__((address_space(3))) void*)l, 16, 0, 0);
}

__device__ __forceinline__ float block_sum(float v, float* buf) {
  #pragma unroll
  for (int off = 32; off > 0; off >>= 1) v += __shfl_xor(v, off);
  __syncthreads();
  if ((threadIdx.x & 63) == 0) buf[threadIdx.x >> 6] = v;
  __syncthreads();
  return buf[0] + buf[1] + buf[2] + buf[3];
}

// ---------------- weight transpose: in f32 [K,N] -> out bf16 [N,K] ----------------
__global__ __launch_bounds__(256) void transpose_kernel(
    const float* __restrict__ in, bf16* __restrict__ out, int K, int N) {
  __shared__ float tile[32][33];
  const int nbx = N >> 5;
  const int bx = blockIdx.x % nbx, by = blockIdx.x / nbx;
  const int tx = threadIdx.x & 31, ty = threadIdx.x >> 5;
  #pragma unroll
  for (int i = 0; i < 4; ++i) {
    const int r = by * 32 + ty + i * 8;
    tile[ty + i * 8][tx] = in[(size_t)r * N + bx * 32 + tx];
  }
  __syncthreads();
  #pragma unroll
  for (int i = 0; i < 4; ++i) {
    const int r = bx * 32 + ty + i * 8;
    out[(size_t)r * K + by * 32 + tx] = f2b(tile[tx][ty + i * 8]);
  }
}

__global__ __launch_bounds__(256) void biasqkv_kernel(
    const float* __restrict__ bq, const float* __restrict__ bk,
    const float* __restrict__ bv, float* __restrict__ out) {
  const int i = blockIdx.x * 256 + threadIdx.x;
  if (i >= 2 * 2304) return;
  const int l = i / 2304, n = i % 2304;
  float v = (n < 768) ? bq[l * 768 + n]
          : (n < 1536) ? bk[l * 768 + n - 768] : bv[l * 768 + n - 1536];
  out[i] = v;
}

// ---------------- conv patchify: 8 tokens per block (f32 in -> bf16 e) ----------------
__global__ __launch_bounds__(256) void patchify_kernel(
    const float* __restrict__ in, const float* __restrict__ w,
    const float* __restrict__ cb, bf16* __restrict__ e) {
  __shared__ float patch[8][64];
  const int tid = threadIdx.x;
  const int tok0 = blockIdx.x * 8;
  for (int idx = tid; idx < 512; idx += 256) {
    const int t = idx >> 6, p = idx & 63;
    const int tok = tok0 + t;
    const int b = tok >> 6, t2 = tok & 63, tt = t2 >> 2, ss = t2 & 3;
    const int kt = p >> 4, kf = p & 15;
    patch[t][p] = in[((size_t)b * 64 + tt * 4 + kt) * 64 + ss * 16 + kf];
  }
  __syncthreads();
  for (int i = 0; i < 3; ++i) {
    const int d = tid + i * 256;
    const float cbv = cb[d];
    float acc[8];
    #pragma unroll
    for (int t = 0; t < 8; ++t) acc[t] = cbv;
    for (int p = 0; p < 64; ++p) {
      const float wv = w[p * 768 + d];
      #pragma unroll
      for (int t = 0; t < 8; ++t) acc[t] += patch[t][p] * wv;
    }
    #pragma unroll
    for (int t = 0; t < 8; ++t) e[(size_t)(tok0 + t) * 768 + d] = f2b(acc[t]);
  }
}

// ---------------- mask + shuffle + pos-embed + LN + agg prepend ----------------
__global__ __launch_bounds__(256) void embed_kernel(
    const bf16* __restrict__ e, const float* __restrict__ randomness,
    const int* __restrict__ perm, const float* __restrict__ temp_embd,
    const float* __restrict__ spec_embd, const float* __restrict__ pls,
    const float* __restrict__ plb, const float* __restrict__ mask_tok,
    const float* __restrict__ agg_tok, bf16* __restrict__ h) {
  __shared__ float rbuf[4];
  const int row = blockIdx.x;       // b*65 + s
  const int b = row / 65, s = row % 65;
  const int tid = threadIdx.x;
  const size_t ob = (size_t)row * 768;
  if (s == 0) {
    #pragma unroll
    for (int i = 0; i < 3; ++i) { const int d = tid + i * 256; h[ob + d] = f2b(agg_tok[d]); }
    return;
  }
  const int tok = s - 1;
  const int gt = b * 64 + tok;
  const float r0 = randomness[gt * 3 + 0];
  const float r1 = randomness[gt * 3 + 1];
  const float r2 = randomness[gt * 3 + 2];
  const bool selb = (r0 <= 0.2f);
  const bool mflag = selb && (r1 <= 0.8f);
  const bool rflag = selb && (r1 > 0.8f) && (r2 <= 0.5f);
  const int src = rflag ? perm[gt] : gt;
  const int tt = tok >> 2, ss2 = tok & 3;
  float v[3]; float sum = 0.f;
  #pragma unroll
  for (int i = 0; i < 3; ++i) {
    const int d = tid + i * 256;
    const float ev = mflag ? mask_tok[d] : b2f(e[(size_t)src * 768 + d]);
    v[i] = ev + temp_embd[tt * 768 + d] + spec_embd[ss2 * 768 + d];
    sum += v[i];
  }
  const float mu = block_sum(sum, rbuf) * (1.f / 768.f);
  float q = 0.f;
  #pragma unroll
  for (int i = 0; i < 3; ++i) { const float t = v[i] - mu; q += t * t; }
  const float rstd = rsqrtf(block_sum(q, rbuf) * (1.f / 768.f) + 1e-6f);
  #pragma unroll
  for (int i = 0; i < 3; ++i) {
    const int d = tid + i * 256;
    h[ob + d] = f2b((v[i] - mu) * rstd * pls[d] + plb[d]);
  }
}

// ---------------- residual + LN (bf16 in, bf16 or f32 out) ----------------
template <int F32OUT>
__global__ __launch_bounds__(256) void resln_kernel(
    const bf16* __restrict__ x, const bf16* __restrict__ y,
    const float* __restrict__ sc, const float* __restrict__ bi,
    void* __restrict__ outp) {
  __shared__ float rbuf[4];
  const int tid = threadIdx.x;
  const size_t base = (size_t)blockIdx.x * 768;
  float v[3]; float s = 0.f;
  #pragma unroll
  for (int i = 0; i < 3; ++i) {
    const int d = tid + i * 256;
    v[i] = b2f(x[base + d]) + b2f(y[base + d]);
    s += v[i];
  }
  const float mu = block_sum(s, rbuf) * (1.f / 768.f);
  float q = 0.f;
  #pragma unroll
  for (int i = 0; i < 3; ++i) { const float t = v[i] - mu; q += t * t; }
  const float rstd = rsqrtf(block_sum(q, rbuf) * (1.f / 768.f) + 1e-6f);
  #pragma unroll
  for (int i = 0; i < 3; ++i) {
    const int d = tid + i * 256;
    const float o = (v[i] - mu) * rstd * sc[d] + bi[d];
    if (F32OUT) ((float*)outp)[base + d] = o;
    else        ((bf16*)outp)[base + d] = f2b(o);
  }
}

// ---------------- GEMM: C[M,N] = act(A[M,K] @ BT[N,K]^T + bias) ----------------
// m97 structure: 128x128 tile, BK=32, 4 waves 2x2, 16x16x32 bf16 MFMA,
// global_load_lds width 16. M multiple of 128, N multiple of 128, K of 32.
template <int ACT>
__global__ __launch_bounds__(256, 2) void gemm_bt_kernel(
    const unsigned short* __restrict__ A, const unsigned short* __restrict__ BT,
    const float* __restrict__ bias, bf16* __restrict__ C, int N, int K) {
  __shared__ __align__(16) unsigned short lA[128 * 32];
  __shared__ __align__(16) unsigned short lB[128 * 32];
  const int tid = threadIdx.x;
  const int wid = tid >> 6, lane = tid & 63;
  const int nbn = N >> 7;
  const int bm = blockIdx.x / nbn, bn = blockIdx.x % nbn;
  const int wm = (wid >> 1) << 6, wn = (wid & 1) << 6;

  const size_t Kb = (size_t)K * 2;
  const char* gA = (const char*)A + (size_t)bm * 128 * Kb;
  const char* gB = (const char*)BT + (size_t)bn * 128 * Kb;
  const int r0 = tid >> 2;
  const int c0 = (tid & 3) * 16;
  char* lAw = (char*)lA + wid * 1024;
  char* lBw = (char*)lB + wid * 1024;

  const f32x4 z = {0.f, 0.f, 0.f, 0.f};
  f32x4 acc[4][4];
  #pragma unroll
  for (int i = 0; i < 4; ++i)
    #pragma unroll
    for (int j = 0; j < 4; ++j) acc[i][j] = z;

  const int frow = lane & 15;
  const int koff = (lane >> 4) * 8;

  for (int k0 = 0; k0 < K; k0 += 32) {
    const char* ga = gA + (size_t)k0 * 2 + c0;
    const char* gb = gB + (size_t)k0 * 2 + c0;
    gload_lds16(ga + (size_t)r0 * Kb, lAw);
    gload_lds16(ga + (size_t)(r0 + 64) * Kb, lAw + 4096);
    gload_lds16(gb + (size_t)r0 * Kb, lBw);
    gload_lds16(gb + (size_t)(r0 + 64) * Kb, lBw + 4096);
    __syncthreads();
    bf16x8v af[4], bfv[4];
    #pragma unroll
    for (int m = 0; m < 4; ++m)
      af[m] = *(const bf16x8v*)&lA[(wm + m * 16 + frow) * 32 + koff];
    #pragma unroll
    for (int n = 0; n < 4; ++n)
      bfv[n] = *(const bf16x8v*)&lB[(wn + n * 16 + frow) * 32 + koff];
    #pragma unroll
    for (int m = 0; m < 4; ++m)
      #pragma unroll
      for (int n = 0; n < 4; ++n)
        acc[m][n] = __builtin_amdgcn_mfma_f32_16x16x32_bf16(af[m], bfv[n], acc[m][n], 0, 0, 0);
    __syncthreads();
  }

  const int row0 = bm * 128 + wm + ((lane >> 4) << 2);
  const int col0 = bn * 128 + wn + frow;
  #pragma unroll
  for (int n = 0; n < 4; ++n) {
    const int col = col0 + n * 16;
    const float bv = bias[col];
    #pragma unroll
    for (int m = 0; m < 4; ++m) {
      const int row = row0 + m * 16;
      #pragma unroll
      for (int r = 0; r < 4; ++r) {
        float v = acc[m][n][r] + bv;
        if (ACT == 1) v = 0.5f * v * (1.0f + erff(v * 0.70710678f));
        C[(size_t)(row + r) * N + col] = f2b(v);
      }
    }
  }
}

// ---------------- attention: one block per (batch, head) ----------------
__global__ __launch_bounds__(256) void attn_kernel(
    const bf16* __restrict__ qkv, bf16* __restrict__ ctx) {
  const int b = blockIdx.x / 12, h = blockIdx.x % 12;
  __shared__ __align__(16) float sq[65][64];
  __shared__ __align__(16) float sk[65][64];
  __shared__ __align__(16) float sv[65][64];
  __shared__ __align__(16) float sp[65][68];
  const int tid = threadIdx.x;
  const size_t gbase = (size_t)b * 65 * 2304 + h * 64;
  for (int idx = tid; idx < 65 * 64; idx += 256) {
    const int si = idx >> 6, d = idx & 63;
    const size_t g = gbase + (size_t)si * 2304 + d;
    sq[si][d] = b2f(qkv[g]) * 0.125f;
    sk[si][d] = b2f(qkv[g + 768]);
    sv[si][d] = b2f(qkv[g + 1536]);
  }
  __syncthreads();
  // scores: 4x4 register tiles over 17x17 tile grid
  for (int blk = tid; blk < 289; blk += 256) {
    const int ti = (blk / 17) * 4, tj = (blk % 17) * 4;
    float a[4][4] = {};
    for (int d4 = 0; d4 < 16; ++d4) {
      f32x4 q4[4], k4[4];
      #pragma unroll
      for (int r = 0; r < 4; ++r) {
        int qi = ti + r; if (qi > 64) qi = 64;
        q4[r] = *(const f32x4*)&sq[qi][d4 * 4];
      }
      #pragma unroll
      for (int c = 0; c < 4; ++c) {
        int kj = tj + c; if (kj > 64) kj = 64;
        k4[c] = *(const f32x4*)&sk[kj][d4 * 4];
      }
      #pragma unroll
      for (int r = 0; r < 4; ++r)
        #pragma unroll
        for (int c = 0; c < 4; ++c)
          a[r][c] += q4[r][0] * k4[c][0] + q4[r][1] * k4[c][1] +
                     q4[r][2] * k4[c][2] + q4[r][3] * k4[c][3];
    }
    #pragma unroll
    for (int r = 0; r < 4; ++r)
      #pragma unroll
      for (int c = 0; c < 4; ++c)
        if (ti + r < 65 && tj + c < 65) sp[ti + r][tj + c] = a[r][c];
  }
  __syncthreads();
  // softmax rows (one wave per row)
  const int lane = tid & 63, w = tid >> 6;
  for (int row = w; row < 65; row += 4) {
    const float x = sp[row][lane];
    const float x64 = sp[row][64];
    float mx = (lane == 0) ? fmaxf(x, x64) : x;
    #pragma unroll
    for (int off = 32; off > 0; off >>= 1) mx = fmaxf(mx, __shfl_xor(mx, off));
    const float ex = expf(x - mx);
    const float e64 = expf(x64 - mx);
    float sm = ex + ((lane == 0) ? e64 : 0.f);
    #pragma unroll
    for (int off = 32; off > 0; off >>= 1) sm += __shfl_xor(sm, off);
    const float inv = 1.f / sm;
    sp[row][lane] = ex * inv;
    if (lane == 0) sp[row][64] = e64 * inv;
  }
  __syncthreads();
  // PV: 4x4 tiles over 17x16 tile grid
  for (int blk = tid; blk < 272; blk += 256) {
    const int ti = (blk / 16) * 4, d0 = (blk % 16) * 4;
    float a[4][4] = {};
    for (int j = 0; j < 65; ++j) {
      const f32x4 vc = *(const f32x4*)&sv[j][d0];
      float pr[4];
      #pragma unroll
      for (int r = 0; r < 4; ++r) {
        int qi = ti + r; if (qi > 64) qi = 64;
        pr[r] = sp[qi][j];
      }
      #pragma unroll
      for (int r = 0; r < 4; ++r)
        #pragma unroll
        for (int c = 0; c < 4; ++c) a[r][c] += pr[r] * vc[c];
    }
    #pragma unroll
    for (int r = 0; r < 4; ++r) {
      const int qi = ti + r;
      if (qi < 65) {
        #pragma unroll
        for (int c = 0; c < 4; ++c)
          ctx[((size_t)b * 65 + qi) * 768 + h * 64 + d0 + c] = f2b(a[r][c]);
      }
    }
  }
}

extern "C" void kernel_launch(void* const* d_in, const int* in_sizes, int n_in,
                              void* d_out, int out_size, void* d_ws, size_t ws_size,
                              hipStream_t stream) {
  (void)in_sizes; (void)n_in; (void)out_size; (void)ws_size;
  const float* inputs     = (const float*)d_in[0];
  const float* randomness = (const float*)d_in[1];
  const int*   perm       = (const int*)d_in[2];
  const float* conv_w     = (const float*)d_in[3];
  const float* conv_b     = (const float*)d_in[4];
  const float* temp_embd  = (const float*)d_in[5];
  const float* spec_embd  = (const float*)d_in[6];
  const float* pos_ln_s   = (const float*)d_in[7];
  const float* pos_ln_b   = (const float*)d_in[8];
  const float* mask_tok   = (const float*)d_in[9];
  const float* agg_tok    = (const float*)d_in[10];
  const float* Wq = (const float*)d_in[11]; const float* bq = (const float*)d_in[12];
  const float* Wk = (const float*)d_in[13]; const float* bk = (const float*)d_in[14];
  const float* Wv = (const float*)d_in[15]; const float* bv = (const float*)d_in[16];
  const float* Wo = (const float*)d_in[17]; const float* bo = (const float*)d_in[18];
  const float* ln1_s = (const float*)d_in[19]; const float* ln1_b = (const float*)d_in[20];
  const float* W1 = (const float*)d_in[21]; const float* b1 = (const float*)d_in[22];
  const float* W2 = (const float*)d_in[23]; const float* b2 = (const float*)d_in[24];
  const float* ln2_s = (const float*)d_in[25]; const float* ln2_b = (const float*)d_in[26];

  char* wsb = (char*)d_ws;
  size_t off = 0;
  auto carve = [&](size_t bytes) { char* p = wsb + off; off = (off + bytes + 255) & ~(size_t)255; return p; };
  bf16* wqkvT = (bf16*)carve((size_t)2 * 2304 * 768 * 2);
  bf16* woT   = (bf16*)carve((size_t)2 * 768 * 768 * 2);
  bf16* w1T   = (bf16*)carve((size_t)2 * 3072 * 768 * 2);
  bf16* w2T   = (bf16*)carve((size_t)2 * 768 * 3072 * 2);
  float* bqkv = (float*)carve((size_t)2 * 2304 * 4);
  bf16* ebuf  = (bf16*)carve((size_t)16640 * 768 * 2);
  bf16* hbuf  = (bf16*)carve((size_t)16640 * 768 * 2);
  bf16* qkvb  = (bf16*)carve((size_t)16640 * 2304 * 2);
  bf16* ctxb  = (bf16*)carve((size_t)16640 * 768 * 2);
  bf16* tmpb  = ebuf;   // e is dead after embed_kernel
  bf16* midb  = qkvb;   // FFN mid [16640,3072] fits in qkv span + slack

  const dim3 blk(256);
  for (int l = 0; l < 2; ++l) {
    transpose_kernel<<<576, blk, 0, stream>>>(Wq + (size_t)l * 768 * 768, wqkvT + (size_t)l * 2304 * 768, 768, 768);
    transpose_kernel<<<576, blk, 0, stream>>>(Wk + (size_t)l * 768 * 768, wqkvT + (size_t)l * 2304 * 768 + 768 * 768, 768, 768);
    transpose_kernel<<<576, blk, 0, stream>>>(Wv + (size_t)l * 768 * 768, wqkvT + (size_t)l * 2304 * 768 + 2 * 768 * 768, 768, 768);
    transpose_kernel<<<576, blk, 0, stream>>>(Wo + (size_t)l * 768 * 768, woT + (size_t)l * 768 * 768, 768, 768);
    transpose_kernel<<<2304, blk, 0, stream>>>(W1 + (size_t)l * 768 * 3072, w1T + (size_t)l * 3072 * 768, 768, 3072);
    transpose_kernel<<<2304, blk, 0, stream>>>(W2 + (size_t)l * 3072 * 768, w2T + (size_t)l * 768 * 3072, 3072, 768);
  }
  biasqkv_kernel<<<18, blk, 0, stream>>>(bq, bk, bv, bqkv);
  patchify_kernel<<<2048, blk, 0, stream>>>(inputs, conv_w, conv_b, ebuf);
  embed_kernel<<<16640, blk, 0, stream>>>(ebuf, randomness, perm, temp_embd, spec_embd,
                                          pos_ln_s, pos_ln_b, mask_tok, agg_tok, hbuf);
  for (int l = 0; l < 2; ++l) {
    gemm_bt_kernel<0><<<130 * 18, blk, 0, stream>>>(
        (const unsigned short*)hbuf, (const unsigned short*)(wqkvT + (size_t)l * 2304 * 768),
        bqkv + l * 2304, qkvb, 2304, 768);
    attn_kernel<<<256 * 12, blk, 0, stream>>>(qkvb, ctxb);
    gemm_bt_kernel<0><<<130 * 6, blk, 0, stream>>>(
        (const unsigned short*)ctxb, (const unsigned short*)(woT + (size_t)l * 768 * 768),
        bo + l * 768, tmpb, 768, 768);
    resln_kernel<0><<<16640, blk, 0, stream>>>(hbuf, tmpb, ln1_s + l * 768, ln1_b + l * 768, hbuf);
    gemm_bt_kernel<1><<<130 * 24, blk, 0, stream>>>(
        (const unsigned short*)hbuf, (const unsigned short*)(w1T + (size_t)l * 3072 * 768),
        b1 + l * 3072, midb, 3072, 768);
    gemm_bt_kernel<0><<<130 * 6, blk, 0, stream>>>(
        (const unsigned short*)midb, (const unsigned short*)(w2T + (size_t)l * 768 * 3072),
        b2 + l * 768, tmpb, 768, 3072);
    if (l == 1)
      resln_kernel<1><<<16640, blk, 0, stream>>>(hbuf, tmpb, ln2_s + l * 768, ln2_b + l * 768, d_out);
    else
      resln_kernel<0><<<16640, blk, 0, stream>>>(hbuf, tmpb, ln2_s + l * 768, ln2_b + l * 768, hbuf);
  }
}

// Round 3
// 1052.127 us; speedup vs baseline: 2.0543x; 2.0543x over previous
//
#include <hip/hip_runtime.h>
#include <hip/hip_bf16.h>
#include <math.h>

using bf16 = __hip_bfloat16;
typedef __bf16 bf16x8v __attribute__((ext_vector_type(8)));
typedef float f32x4 __attribute__((ext_vector_type(4)));
typedef unsigned short ushort4v __attribute__((ext_vector_type(4)));

__device__ __forceinline__ float b2f(bf16 x) { return __bfloat162float(x); }
__device__ __forceinline__ bf16 f2b(float x) { return __float2bfloat16(x); }

__device__ __forceinline__ void gload_lds16(const void* g, void* l) {
  __builtin_amdgcn_global_load_lds(
      (__attribute__((address_space(1))) void*)(void*)g,
      (__attribute__((address_space(3))) void*)l, 16, 0, 0);
}

__device__ __forceinline__ float block_sum(float v, float* buf) {
  #pragma unroll
  for (int off = 32; off > 0; off >>= 1) v += __shfl_xor(v, off);
  __syncthreads();
  if ((threadIdx.x & 63) == 0) buf[threadIdx.x >> 6] = v;
  __syncthreads();
  return buf[0] + buf[1] + buf[2] + buf[3];
}

// ---------------- weight transpose: in f32 [K,N] -> out bf16 [N,K] ----------------
__global__ __launch_bounds__(256) void transpose_kernel(
    const float* __restrict__ in, bf16* __restrict__ out, int K, int N) {
  __shared__ float tile[32][33];
  const int nbx = N >> 5;
  const int bx = blockIdx.x % nbx, by = blockIdx.x / nbx;
  const int tx = threadIdx.x & 31, ty = threadIdx.x >> 5;
  #pragma unroll
  for (int i = 0; i < 4; ++i) {
    const int r = by * 32 + ty + i * 8;
    tile[ty + i * 8][tx] = in[(size_t)r * N + bx * 32 + tx];
  }
  __syncthreads();
  #pragma unroll
  for (int i = 0; i < 4; ++i) {
    const int r = bx * 32 + ty + i * 8;
    out[(size_t)r * K + by * 32 + tx] = f2b(tile[tx][ty + i * 8]);
  }
}

__global__ __launch_bounds__(256) void biasqkv_kernel(
    const float* __restrict__ bq, const float* __restrict__ bk,
    const float* __restrict__ bv, float* __restrict__ out) {
  const int i = blockIdx.x * 256 + threadIdx.x;
  if (i >= 2 * 2304) return;
  const int l = i / 2304, n = i % 2304;
  float v = (n < 768) ? bq[l * 768 + n]
          : (n < 1536) ? bk[l * 768 + n - 768] : bv[l * 768 + n - 1536];
  out[i] = v;
}

// ---------------- conv patchify: 8 tokens per block (f32 in -> bf16 e) ----------------
__global__ __launch_bounds__(256) void patchify_kernel(
    const float* __restrict__ in, const float* __restrict__ w,
    const float* __restrict__ cb, bf16* __restrict__ e) {
  __shared__ float patch[8][64];
  const int tid = threadIdx.x;
  const int tok0 = blockIdx.x * 8;
  for (int idx = tid; idx < 512; idx += 256) {
    const int t = idx >> 6, p = idx & 63;
    const int tok = tok0 + t;
    const int b = tok >> 6, t2 = tok & 63, tt = t2 >> 2, ss = t2 & 3;
    const int kt = p >> 4, kf = p & 15;
    patch[t][p] = in[((size_t)b * 64 + tt * 4 + kt) * 64 + ss * 16 + kf];
  }
  __syncthreads();
  for (int i = 0; i < 3; ++i) {
    const int d = tid + i * 256;
    const float cbv = cb[d];
    float acc[8];
    #pragma unroll
    for (int t = 0; t < 8; ++t) acc[t] = cbv;
    for (int p = 0; p < 64; ++p) {
      const float wv = w[p * 768 + d];
      #pragma unroll
      for (int t = 0; t < 8; ++t) acc[t] += patch[t][p] * wv;
    }
    #pragma unroll
    for (int t = 0; t < 8; ++t) e[(size_t)(tok0 + t) * 768 + d] = f2b(acc[t]);
  }
}

// ---------------- mask + shuffle + pos-embed + LN + agg prepend ----------------
__global__ __launch_bounds__(256) void embed_kernel(
    const bf16* __restrict__ e, const float* __restrict__ randomness,
    const int* __restrict__ perm, const float* __restrict__ temp_embd,
    const float* __restrict__ spec_embd, const float* __restrict__ pls,
    const float* __restrict__ plb, const float* __restrict__ mask_tok,
    const float* __restrict__ agg_tok, bf16* __restrict__ h) {
  __shared__ float rbuf[4];
  const int row = blockIdx.x;       // b*65 + s
  const int b = row / 65, s = row % 65;
  const int tid = threadIdx.x;
  const size_t ob = (size_t)row * 768;
  if (s == 0) {
    #pragma unroll
    for (int i = 0; i < 3; ++i) { const int d = tid + i * 256; h[ob + d] = f2b(agg_tok[d]); }
    return;
  }
  const int tok = s - 1;
  const int gt = b * 64 + tok;
  const float r0 = randomness[gt * 3 + 0];
  const float r1 = randomness[gt * 3 + 1];
  const float r2 = randomness[gt * 3 + 2];
  const bool selb = (r0 <= 0.2f);
  const bool mflag = selb && (r1 <= 0.8f);
  const bool rflag = selb && (r1 > 0.8f) && (r2 <= 0.5f);
  const int src = rflag ? perm[gt] : gt;
  const int tt = tok >> 2, ss2 = tok & 3;
  float v[3]; float sum = 0.f;
  #pragma unroll
  for (int i = 0; i < 3; ++i) {
    const int d = tid + i * 256;
    const float ev = mflag ? mask_tok[d] : b2f(e[(size_t)src * 768 + d]);
    v[i] = ev + temp_embd[tt * 768 + d] + spec_embd[ss2 * 768 + d];
    sum += v[i];
  }
  const float mu = block_sum(sum, rbuf) * (1.f / 768.f);
  float q = 0.f;
  #pragma unroll
  for (int i = 0; i < 3; ++i) { const float t = v[i] - mu; q += t * t; }
  const float rstd = rsqrtf(block_sum(q, rbuf) * (1.f / 768.f) + 1e-6f);
  #pragma unroll
  for (int i = 0; i < 3; ++i) {
    const int d = tid + i * 256;
    h[ob + d] = f2b((v[i] - mu) * rstd * pls[d] + plb[d]);
  }
}

// ---------------- residual + LN (bf16 in, bf16 or f32 out) ----------------
template <int F32OUT>
__global__ __launch_bounds__(256) void resln_kernel(
    const bf16* __restrict__ x, const bf16* __restrict__ y,
    const float* __restrict__ sc, const float* __restrict__ bi,
    void* __restrict__ outp) {
  __shared__ float rbuf[4];
  const int tid = threadIdx.x;
  const size_t base = (size_t)blockIdx.x * 768;
  float v[3]; float s = 0.f;
  #pragma unroll
  for (int i = 0; i < 3; ++i) {
    const int d = tid + i * 256;
    v[i] = b2f(x[base + d]) + b2f(y[base + d]);
    s += v[i];
  }
  const float mu = block_sum(s, rbuf) * (1.f / 768.f);
  float q = 0.f;
  #pragma unroll
  for (int i = 0; i < 3; ++i) { const float t = v[i] - mu; q += t * t; }
  const float rstd = rsqrtf(block_sum(q, rbuf) * (1.f / 768.f) + 1e-6f);
  #pragma unroll
  for (int i = 0; i < 3; ++i) {
    const int d = tid + i * 256;
    const float o = (v[i] - mu) * rstd * sc[d] + bi[d];
    if (F32OUT) ((float*)outp)[base + d] = o;
    else        ((bf16*)outp)[base + d] = f2b(o);
  }
}

// ---------------- GEMM: C[M,N] = act(A[M,K] @ BT[N,K]^T + bias) ----------------
template <int ACT>
__global__ __launch_bounds__(256, 2) void gemm_bt_kernel(
    const unsigned short* __restrict__ A, const unsigned short* __restrict__ BT,
    const float* __restrict__ bias, bf16* __restrict__ C, int N, int K) {
  __shared__ __align__(16) unsigned short lA[128 * 32];
  __shared__ __align__(16) unsigned short lB[128 * 32];
  const int tid = threadIdx.x;
  const int wid = tid >> 6, lane = tid & 63;
  const int nbn = N >> 7;
  const int bm = blockIdx.x / nbn, bn = blockIdx.x % nbn;
  const int wm = (wid >> 1) << 6, wn = (wid & 1) << 6;

  const size_t Kb = (size_t)K * 2;
  const char* gA = (const char*)A + (size_t)bm * 128 * Kb;
  const char* gB = (const char*)BT + (size_t)bn * 128 * Kb;
  const int r0 = tid >> 2;
  const int c0 = (tid & 3) * 16;
  char* lAw = (char*)lA + wid * 1024;
  char* lBw = (char*)lB + wid * 1024;

  const f32x4 z = {0.f, 0.f, 0.f, 0.f};
  f32x4 acc[4][4];
  #pragma unroll
  for (int i = 0; i < 4; ++i)
    #pragma unroll
    for (int j = 0; j < 4; ++j) acc[i][j] = z;

  const int frow = lane & 15;
  const int koff = (lane >> 4) * 8;

  for (int k0 = 0; k0 < K; k0 += 32) {
    const char* ga = gA + (size_t)k0 * 2 + c0;
    const char* gb = gB + (size_t)k0 * 2 + c0;
    gload_lds16(ga + (size_t)r0 * Kb, lAw);
    gload_lds16(ga + (size_t)(r0 + 64) * Kb, lAw + 4096);
    gload_lds16(gb + (size_t)r0 * Kb, lBw);
    gload_lds16(gb + (size_t)(r0 + 64) * Kb, lBw + 4096);
    __syncthreads();
    bf16x8v af[4], bfv[4];
    #pragma unroll
    for (int m = 0; m < 4; ++m)
      af[m] = *(const bf16x8v*)&lA[(wm + m * 16 + frow) * 32 + koff];
    #pragma unroll
    for (int n = 0; n < 4; ++n)
      bfv[n] = *(const bf16x8v*)&lB[(wn + n * 16 + frow) * 32 + koff];
    #pragma unroll
    for (int m = 0; m < 4; ++m)
      #pragma unroll
      for (int n = 0; n < 4; ++n)
        acc[m][n] = __builtin_amdgcn_mfma_f32_16x16x32_bf16(af[m], bfv[n], acc[m][n], 0, 0, 0);
    __syncthreads();
  }

  const int row0 = bm * 128 + wm + ((lane >> 4) << 2);
  const int col0 = bn * 128 + wn + frow;
  #pragma unroll
  for (int n = 0; n < 4; ++n) {
    const int col = col0 + n * 16;
    const float bv = bias[col];
    #pragma unroll
    for (int m = 0; m < 4; ++m) {
      const int row = row0 + m * 16;
      #pragma unroll
      for (int r = 0; r < 4; ++r) {
        float v = acc[m][n][r] + bv;
        if (ACT == 1) v = 0.5f * v * (1.0f + erff(v * 0.70710678f));
        C[(size_t)(row + r) * N + col] = f2b(v);
      }
    }
  }
}

// ---------------- MFMA attention: one block per (batch, head), 5 waves ----------------
// Q,K,V [65,64] bf16, padded to 80 rows / 96 k. Wave w owns output rows w*16..w*16+15.
// QK^T: A=Q frags from global, B=K rows staged in LDS (BT layout, pad stride 72).
// softmax in-register on C-layout (col=lane&15, row=(lane>>4)*4+r), intra-16-lane shfl.
// PV: P in per-wave LDS [16][104], V staged transposed sVt[64][104].
__global__ __launch_bounds__(320) void attn_mfma_kernel(
    const bf16* __restrict__ qkv, bf16* __restrict__ ctx) {
  __shared__ __align__(16) bf16 sK[80][72];
  __shared__ __align__(16) bf16 sVt[64][104];
  __shared__ __align__(16) bf16 sP[5][16][104];
  const int b = blockIdx.x / 12, h = blockIdx.x % 12;
  const int tid = threadIdx.x;
  const int wave = tid >> 6, lane = tid & 63;
  const size_t base = ((size_t)b * 65) * 2304 + (size_t)h * 64;
  const bf16 bzero = f2b(0.f);

  // stage K (as rows) and V (transposed), 4 d's per thread
  for (int idx = tid; idx < 65 * 16; idx += 320) {
    const int row = idx >> 4, d4 = (idx & 15) * 4;
    const ushort4v kv = *(const ushort4v*)(qkv + base + (size_t)row * 2304 + 768 + d4);
    const ushort4v vv = *(const ushort4v*)(qkv + base + (size_t)row * 2304 + 1536 + d4);
    *(ushort4v*)&sK[row][d4] = kv;
    #pragma unroll
    for (int j = 0; j < 4; ++j) ((unsigned short*)&sVt[d4 + j][row])[0] = vv[j];
  }
  // zero pads: K rows 65..79 (cols 0..63), Vt cols 65..95 (all d)
  for (int idx = tid; idx < 15 * 16; idx += 320) {
    const int row = 65 + (idx >> 4), d4 = (idx & 15) * 4;
    *(ushort4v*)&sK[row][d4] = ushort4v{0, 0, 0, 0};
  }
  for (int idx = tid; idx < 64 * 8; idx += 320) {
    const int d = idx >> 3, c4 = 64 + (idx & 7) * 4;   // cols 64..95 (64 re-zero ok? no! col 64 is valid)
    // careful: col 64 holds V row 64 (valid). zero only 68..95 via offset:
    (void)d; (void)c4;
  }
  // zero Vt cols 65..95 precisely (31 cols per d): 64*31 = 1984 scalar stores
  for (int idx = tid; idx < 64 * 31; idx += 320) {
    const int d = idx / 31, c = 65 + (idx % 31);
    sVt[d][c] = bzero;
  }
  __syncthreads();

  const int frow = lane & 15;
  const int koff = (lane >> 4) * 8;
  const int row0 = wave * 16;
  const int qrow = (row0 + frow > 64) ? 64 : (row0 + frow);
  const bf16* qptr = qkv + base + (size_t)qrow * 2304;
  const bf16x8v aq0 = *(const bf16x8v*)(qptr + koff);
  const bf16x8v aq1 = *(const bf16x8v*)(qptr + 32 + koff);

  // scores: 5 col-tiles x 2 k-steps
  const f32x4 z4 = {0.f, 0.f, 0.f, 0.f};
  f32x4 sacc[5];
  #pragma unroll
  for (int n = 0; n < 5; ++n) sacc[n] = z4;
  #pragma unroll
  for (int n = 0; n < 5; ++n) {
    const bf16x8v b0 = *(const bf16x8v*)&sK[n * 16 + frow][koff];
    const bf16x8v b1 = *(const bf16x8v*)&sK[n * 16 + frow][32 + koff];
    sacc[n] = __builtin_amdgcn_mfma_f32_16x16x32_bf16(aq0, b0, sacc[n], 0, 0, 0);
    sacc[n] = __builtin_amdgcn_mfma_f32_16x16x32_bf16(aq1, b1, sacc[n], 0, 0, 0);
  }

  // softmax per output row (4 rows per lane-group), intra-16-lane reduction
  #pragma unroll
  for (int r = 0; r < 4; ++r) {
    const int prow = ((lane >> 4) << 2) + r;
    float v[5];
    float mx = -1e30f;
    #pragma unroll
    for (int n = 0; n < 5; ++n) {
      const int col = n * 16 + frow;
      v[n] = (col < 65) ? sacc[n][r] * 0.125f : -1e30f;
      mx = fmaxf(mx, v[n]);
    }
    #pragma unroll
    for (int off = 1; off < 16; off <<= 1) mx = fmaxf(mx, __shfl_xor(mx, off));
    float sum = 0.f;
    #pragma unroll
    for (int n = 0; n < 5; ++n) { v[n] = __expf(v[n] - mx); sum += v[n]; }
    #pragma unroll
    for (int off = 1; off < 16; off <<= 1) sum += __shfl_xor(sum, off);
    const float inv = 1.f / sum;
    #pragma unroll
    for (int n = 0; n < 5; ++n)
      sP[wave][prow][n * 16 + frow] = f2b(v[n] * inv);
    sP[wave][prow][80 + frow] = bzero;   // cols 80..95
  }

  // PV: O[16,64] = P[16,96] @ V[96,64]; B from sVt (BT layout)
  f32x4 oacc[4];
  #pragma unroll
  for (int n = 0; n < 4; ++n) oacc[n] = z4;
  #pragma unroll
  for (int kk = 0; kk < 3; ++kk) {
    const bf16x8v ap = *(const bf16x8v*)&sP[wave][frow][kk * 32 + koff];
    #pragma unroll
    for (int n = 0; n < 4; ++n) {
      const bf16x8v bv = *(const bf16x8v*)&sVt[n * 16 + frow][kk * 32 + koff];
      oacc[n] = __builtin_amdgcn_mfma_f32_16x16x32_bf16(ap, bv, oacc[n], 0, 0, 0);
    }
  }

  // store O rows < 65
  #pragma unroll
  for (int r = 0; r < 4; ++r) {
    const int row = row0 + ((lane >> 4) << 2) + r;
    if (row < 65) {
      bf16* op = ctx + ((size_t)b * 65 + row) * 768 + (size_t)h * 64 + frow;
      #pragma unroll
      for (int n = 0; n < 4; ++n) op[n * 16] = f2b(oacc[n][r]);
    }
  }
}

extern "C" void kernel_launch(void* const* d_in, const int* in_sizes, int n_in,
                              void* d_out, int out_size, void* d_ws, size_t ws_size,
                              hipStream_t stream) {
  (void)in_sizes; (void)n_in; (void)out_size; (void)ws_size;
  const float* inputs     = (const float*)d_in[0];
  const float* randomness = (const float*)d_in[1];
  const int*   perm       = (const int*)d_in[2];
  const float* conv_w     = (const float*)d_in[3];
  const float* conv_b     = (const float*)d_in[4];
  const float* temp_embd  = (const float*)d_in[5];
  const float* spec_embd  = (const float*)d_in[6];
  const float* pos_ln_s   = (const float*)d_in[7];
  const float* pos_ln_b   = (const float*)d_in[8];
  const float* mask_tok   = (const float*)d_in[9];
  const float* agg_tok    = (const float*)d_in[10];
  const float* Wq = (const float*)d_in[11]; const float* bq = (const float*)d_in[12];
  const float* Wk = (const float*)d_in[13]; const float* bk = (const float*)d_in[14];
  const float* Wv = (const float*)d_in[15]; const float* bv = (const float*)d_in[16];
  const float* Wo = (const float*)d_in[17]; const float* bo = (const float*)d_in[18];
  const float* ln1_s = (const float*)d_in[19]; const float* ln1_b = (const float*)d_in[20];
  const float* W1 = (const float*)d_in[21]; const float* b1 = (const float*)d_in[22];
  const float* W2 = (const float*)d_in[23]; const float* b2 = (const float*)d_in[24];
  const float* ln2_s = (const float*)d_in[25]; const float* ln2_b = (const float*)d_in[26];

  char* wsb = (char*)d_ws;
  size_t off = 0;
  auto carve = [&](size_t bytes) { char* p = wsb + off; off = (off + bytes + 255) & ~(size_t)255; return p; };
  bf16* wqkvT = (bf16*)carve((size_t)2 * 2304 * 768 * 2);
  bf16* woT   = (bf16*)carve((size_t)2 * 768 * 768 * 2);
  bf16* w1T   = (bf16*)carve((size_t)2 * 3072 * 768 * 2);
  bf16* w2T   = (bf16*)carve((size_t)2 * 768 * 3072 * 2);
  float* bqkv = (float*)carve((size_t)2 * 2304 * 4);
  bf16* ebuf  = (bf16*)carve((size_t)16640 * 768 * 2);
  bf16* hbuf  = (bf16*)carve((size_t)16640 * 768 * 2);
  bf16* qkvb  = (bf16*)carve((size_t)16640 * 2304 * 2);
  bf16* ctxb  = (bf16*)carve((size_t)16640 * 768 * 2);
  bf16* tmpb  = ebuf;   // e is dead after embed_kernel
  bf16* midb  = qkvb;   // FFN mid [16640,3072] fits in qkv span

  const dim3 blk(256);
  for (int l = 0; l < 2; ++l) {
    transpose_kernel<<<576, blk, 0, stream>>>(Wq + (size_t)l * 768 * 768, wqkvT + (size_t)l * 2304 * 768, 768, 768);
    transpose_kernel<<<576, blk, 0, stream>>>(Wk + (size_t)l * 768 * 768, wqkvT + (size_t)l * 2304 * 768 + 768 * 768, 768, 768);
    transpose_kernel<<<576, blk, 0, stream>>>(Wv + (size_t)l * 768 * 768, wqkvT + (size_t)l * 2304 * 768 + 2 * 768 * 768, 768, 768);
    transpose_kernel<<<576, blk, 0, stream>>>(Wo + (size_t)l * 768 * 768, woT + (size_t)l * 768 * 768, 768, 768);
    transpose_kernel<<<2304, blk, 0, stream>>>(W1 + (size_t)l * 768 * 3072, w1T + (size_t)l * 3072 * 768, 768, 3072);
    transpose_kernel<<<2304, blk, 0, stream>>>(W2 + (size_t)l * 3072 * 768, w2T + (size_t)l * 768 * 3072, 3072, 768);
  }
  biasqkv_kernel<<<18, blk, 0, stream>>>(bq, bk, bv, bqkv);
  patchify_kernel<<<2048, blk, 0, stream>>>(inputs, conv_w, conv_b, ebuf);
  embed_kernel<<<16640, blk, 0, stream>>>(ebuf, randomness, perm, temp_embd, spec_embd,
                                          pos_ln_s, pos_ln_b, mask_tok, agg_tok, hbuf);
  for (int l = 0; l < 2; ++l) {
    gemm_bt_kernel<0><<<130 * 18, blk, 0, stream>>>(
        (const unsigned short*)hbuf, (const unsigned short*)(wqkvT + (size_t)l * 2304 * 768),
        bqkv + l * 2304, qkvb, 2304, 768);
    attn_mfma_kernel<<<256 * 12, dim3(320), 0, stream>>>(qkvb, ctxb);
    gemm_bt_kernel<0><<<130 * 6, blk, 0, stream>>>(
        (const unsigned short*)ctxb, (const unsigned short*)(woT + (size_t)l * 768 * 768),
        bo + l * 768, tmpb, 768, 768);
    resln_kernel<0><<<16640, blk, 0, stream>>>(hbuf, tmpb, ln1_s + l * 768, ln1_b + l * 768, hbuf);
    gemm_bt_kernel<1><<<130 * 24, blk, 0, stream>>>(
        (const unsigned short*)hbuf, (const unsigned short*)(w1T + (size_t)l * 3072 * 768),
        b1 + l * 3072, midb, 3072, 768);
    gemm_bt_kernel<0><<<130 * 6, blk, 0, stream>>>(
        (const unsigned short*)midb, (const unsigned short*)(w2T + (size_t)l * 768 * 3072),
        b2 + l * 768, tmpb, 768, 3072);
    if (l == 1)
      resln_kernel<1><<<16640, blk, 0, stream>>>(hbuf, tmpb, ln2_s + l * 768, ln2_b + l * 768, d_out);
    else
      resln_kernel<0><<<16640, blk, 0, stream>>>(hbuf, tmpb, ln2_s + l * 768, ln2_b + l * 768, hbuf);
  }
}

// Round 4
// 966.885 us; speedup vs baseline: 2.2354x; 1.0882x over previous
//
#include <hip/hip_runtime.h>
#include <hip/hip_bf16.h>
#include <math.h>

using bf16 = __hip_bfloat16;
typedef __bf16 bf16x8v __attribute__((ext_vector_type(8)));
typedef float f32x4 __attribute__((ext_vector_type(4)));
typedef unsigned short ushort4v __attribute__((ext_vector_type(4)));
typedef unsigned short ushort8v __attribute__((ext_vector_type(8)));

__device__ __forceinline__ float b2f(bf16 x) { return __bfloat162float(x); }
__device__ __forceinline__ bf16 f2b(float x) { return __float2bfloat16(x); }

__device__ __forceinline__ void gload_lds16(const void* g, void* l) {
  __builtin_amdgcn_global_load_lds(
      (__attribute__((address_space(1))) void*)(void*)g,
      (__attribute__((address_space(3))) void*)l, 16, 0, 0);
}

__device__ __forceinline__ float block_sum(float v, float* buf) {
  #pragma unroll
  for (int off = 32; off > 0; off >>= 1) v += __shfl_xor(v, off);
  __syncthreads();
  if ((threadIdx.x & 63) == 0) buf[threadIdx.x >> 6] = v;
  __syncthreads();
  return buf[0] + buf[1] + buf[2] + buf[3];
}

// ---------------- weight transpose: in f32 [K,N] -> out bf16 [N,K] ----------------
__global__ __launch_bounds__(256) void transpose_kernel(
    const float* __restrict__ in, bf16* __restrict__ out, int K, int N) {
  __shared__ float tile[32][33];
  const int nbx = N >> 5;
  const int bx = blockIdx.x % nbx, by = blockIdx.x / nbx;
  const int tx = threadIdx.x & 31, ty = threadIdx.x >> 5;
  #pragma unroll
  for (int i = 0; i < 4; ++i) {
    const int r = by * 32 + ty + i * 8;
    tile[ty + i * 8][tx] = in[(size_t)r * N + bx * 32 + tx];
  }
  __syncthreads();
  #pragma unroll
  for (int i = 0; i < 4; ++i) {
    const int r = bx * 32 + ty + i * 8;
    out[(size_t)r * K + by * 32 + tx] = f2b(tile[tx][ty + i * 8]);
  }
}

__global__ __launch_bounds__(256) void biasqkv_kernel(
    const float* __restrict__ bq, const float* __restrict__ bk,
    const float* __restrict__ bv, float* __restrict__ out) {
  const int i = blockIdx.x * 256 + threadIdx.x;
  if (i >= 2 * 2304) return;
  const int l = i / 2304, n = i % 2304;
  float v = (n < 768) ? bq[l * 768 + n]
          : (n < 1536) ? bk[l * 768 + n - 768] : bv[l * 768 + n - 1536];
  out[i] = v;
}

// ---------------- conv patchify: 8 tokens per block (f32 in -> bf16 e) ----------------
__global__ __launch_bounds__(256) void patchify_kernel(
    const float* __restrict__ in, const float* __restrict__ w,
    const float* __restrict__ cb, bf16* __restrict__ e) {
  __shared__ float patch[8][64];
  const int tid = threadIdx.x;
  const int tok0 = blockIdx.x * 8;
  for (int idx = tid; idx < 512; idx += 256) {
    const int t = idx >> 6, p = idx & 63;
    const int tok = tok0 + t;
    const int b = tok >> 6, t2 = tok & 63, tt = t2 >> 2, ss = t2 & 3;
    const int kt = p >> 4, kf = p & 15;
    patch[t][p] = in[((size_t)b * 64 + tt * 4 + kt) * 64 + ss * 16 + kf];
  }
  __syncthreads();
  for (int i = 0; i < 3; ++i) {
    const int d = tid + i * 256;
    const float cbv = cb[d];
    float acc[8];
    #pragma unroll
    for (int t = 0; t < 8; ++t) acc[t] = cbv;
    for (int p = 0; p < 64; ++p) {
      const float wv = w[p * 768 + d];
      #pragma unroll
      for (int t = 0; t < 8; ++t) acc[t] += patch[t][p] * wv;
    }
    #pragma unroll
    for (int t = 0; t < 8; ++t) e[(size_t)(tok0 + t) * 768 + d] = f2b(acc[t]);
  }
}

// ---------------- mask + shuffle + pos-embed + LN + agg prepend ----------------
__global__ __launch_bounds__(256) void embed_kernel(
    const bf16* __restrict__ e, const float* __restrict__ randomness,
    const int* __restrict__ perm, const float* __restrict__ temp_embd,
    const float* __restrict__ spec_embd, const float* __restrict__ pls,
    const float* __restrict__ plb, const float* __restrict__ mask_tok,
    const float* __restrict__ agg_tok, bf16* __restrict__ h) {
  __shared__ float rbuf[4];
  const int row = blockIdx.x;       // b*65 + s
  const int b = row / 65, s = row % 65;
  const int tid = threadIdx.x;
  const size_t ob = (size_t)row * 768;
  if (s == 0) {
    #pragma unroll
    for (int i = 0; i < 3; ++i) { const int d = tid + i * 256; h[ob + d] = f2b(agg_tok[d]); }
    return;
  }
  const int tok = s - 1;
  const int gt = b * 64 + tok;
  const float r0 = randomness[gt * 3 + 0];
  const float r1 = randomness[gt * 3 + 1];
  const float r2 = randomness[gt * 3 + 2];
  const bool selb = (r0 <= 0.2f);
  const bool mflag = selb && (r1 <= 0.8f);
  const bool rflag = selb && (r1 > 0.8f) && (r2 <= 0.5f);
  const int src = rflag ? perm[gt] : gt;
  const int tt = tok >> 2, ss2 = tok & 3;
  float v[3]; float sum = 0.f;
  #pragma unroll
  for (int i = 0; i < 3; ++i) {
    const int d = tid + i * 256;
    const float ev = mflag ? mask_tok[d] : b2f(e[(size_t)src * 768 + d]);
    v[i] = ev + temp_embd[tt * 768 + d] + spec_embd[ss2 * 768 + d];
    sum += v[i];
  }
  const float mu = block_sum(sum, rbuf) * (1.f / 768.f);
  float q = 0.f;
  #pragma unroll
  for (int i = 0; i < 3; ++i) { const float t = v[i] - mu; q += t * t; }
  const float rstd = rsqrtf(block_sum(q, rbuf) * (1.f / 768.f) + 1e-6f);
  #pragma unroll
  for (int i = 0; i < 3; ++i) {
    const int d = tid + i * 256;
    h[ob + d] = f2b((v[i] - mu) * rstd * pls[d] + plb[d]);
  }
}

// ---------------- residual + LN (bf16 in, bf16 or f32 out) ----------------
template <int F32OUT>
__global__ __launch_bounds__(256) void resln_kernel(
    const bf16* __restrict__ x, const bf16* __restrict__ y,
    const float* __restrict__ sc, const float* __restrict__ bi,
    void* __restrict__ outp) {
  __shared__ float rbuf[4];
  const int tid = threadIdx.x;
  const size_t base = (size_t)blockIdx.x * 768;
  float v[3]; float s = 0.f;
  #pragma unroll
  for (int i = 0; i < 3; ++i) {
    const int d = tid + i * 256;
    v[i] = b2f(x[base + d]) + b2f(y[base + d]);
    s += v[i];
  }
  const float mu = block_sum(s, rbuf) * (1.f / 768.f);
  float q = 0.f;
  #pragma unroll
  for (int i = 0; i < 3; ++i) { const float t = v[i] - mu; q += t * t; }
  const float rstd = rsqrtf(block_sum(q, rbuf) * (1.f / 768.f) + 1e-6f);
  #pragma unroll
  for (int i = 0; i < 3; ++i) {
    const int d = tid + i * 256;
    const float o = (v[i] - mu) * rstd * sc[d] + bi[d];
    if (F32OUT) ((float*)outp)[base + d] = o;
    else        ((bf16*)outp)[base + d] = f2b(o);
  }
}

// ================= 256-wide double-buffered prefetch GEMM =================
// C[M,N] = act(A[M,K] @ BT[N,K]^T + bias).  BM=256, BN=64*WN, BK=64.
// 512 threads = 8 waves, (8/WN) x WN wave grid, per-wave 256/(8/WN) x 64 output.
// LDS: 2 bufs x (A 32KB + B BN*128B), st_16x32 swizzle (byte ^= ((byte>>9)&1)<<5)
// realized via pre-swizzled global source (gload_lds dest stays linear) +
// swizzled ds_read addresses. Prefetch next K-tile before compute, single
// barrier per K-tile (compiler emits vmcnt(0) drain at the barrier).
// Epilogue: bias+act in reg, repack through padded LDS, 16B coalesced stores.
template <int WN, int ACT>
__global__ __launch_bounds__(512, 2) void gemm256_kernel(
    const unsigned short* __restrict__ A, const unsigned short* __restrict__ BT,
    const float* __restrict__ bias, bf16* __restrict__ C, int N, int K, int nbn) {
  constexpr int WM = 8 / WN;          // waves along M
  constexpr int RPW = 256 / WM;       // rows per wave (128 or 64)
  constexpr int BN = 64 * WN;         // 256 or 128
  constexpr int MF = RPW / 16;        // 8 or 4 M-frags per wave
  constexpr int NF = 4;               // 4 N-frags per wave (64 cols)
  constexpr int ABYTES = 256 * 128;   // 32 KB per A buffer
  constexpr int BBYTES = BN * 128;    // 32 or 16 KB per B buffer
  constexpr int PADC = BN + 4;        // padded epilogue stride (elems)
  constexpr int LOOPB = 2 * (ABYTES + BBYTES);
  constexpr int EPIB = 256 * PADC * 2;
  constexpr int SMEMB = LOOPB > EPIB ? LOOPB : EPIB;
  __shared__ __align__(16) char smem[SMEMB];

  // --- bijective XCD swizzle (m204) ---
  const int nwg = gridDim.x;
  const int orig = blockIdx.x;
  const int q8 = nwg >> 3, r8 = nwg & 7;
  const int xcd = orig & 7, lin = orig >> 3;
  const int bid = (xcd < r8 ? xcd * (q8 + 1) : r8 * (q8 + 1) + (xcd - r8) * q8) + lin;
  const int bm = bid / nbn, bn = bid % nbn;

  const int tid = threadIdx.x;
  const int w = tid >> 6, lane = tid & 63;
  const int wrow = w / WN, wcol = w % WN;
  const int frow = lane & 15;
  const int kgrp = lane & 48;          // (lane>>4)*16 bytes k-offset

  const size_t Kb = (size_t)K * 2;
  // staging source (pre-swizzled): lane chunk -> row = i*64 + w*8 + (lane>>3),
  // colbyte = ((lane&7)*16) ^ (lane&32)
  const int laneRow = lane >> 3;
  const int laneCB = ((lane & 7) << 4) ^ (lane & 32);
  const char* gA = (const char*)A + ((size_t)bm * 256 + w * 8 + laneRow) * Kb + laneCB;
  const char* gB = (const char*)BT + ((size_t)bn * BN + w * 8 + laneRow) * Kb + laneCB;

  f32x4 acc[MF][NF];
  #pragma unroll
  for (int i = 0; i < MF; ++i)
    #pragma unroll
    for (int j = 0; j < NF; ++j) acc[i][j] = f32x4{0.f, 0.f, 0.f, 0.f};

  auto stage = [&](int buf, int kt) {
    const size_t ko = (size_t)kt << 7;   // kt*64 cols * 2B
    char* la = smem + buf * (ABYTES + BBYTES);
    char* lb = la + ABYTES;
    #pragma unroll
    for (int i = 0; i < 4; ++i)
      gload_lds16(gA + (size_t)i * 64 * Kb + ko, la + i * 8192 + w * 1024);
    #pragma unroll
    for (int i = 0; i < BN / 64; ++i)
      gload_lds16(gB + (size_t)i * 64 * Kb + ko, lb + i * 8192 + w * 1024);
  };

  auto compute = [&](int buf) {
    const char* la = smem + buf * (ABYTES + BBYTES);
    const char* lb = la + ABYTES;
    #pragma unroll
    for (int mq = 0; mq < MF / 4; ++mq) {
      bf16x8v af[4][2];
      #pragma unroll
      for (int j = 0; j < 4; ++j)
        #pragma unroll
        for (int s = 0; s < 2; ++s) {
          const int row = wrow * RPW + (mq * 4 + j) * 16 + frow;
          const int cb = (s * 64 + kgrp) ^ (((row >> 2) & 1) << 5);
          af[j][s] = *(const bf16x8v*)(la + row * 128 + cb);
        }
      #pragma unroll
      for (int nq = 0; nq < 2; ++nq) {
        bf16x8v bv[2][2];
        #pragma unroll
        for (int n = 0; n < 2; ++n)
          #pragma unroll
          for (int s = 0; s < 2; ++s) {
            const int row = wcol * 64 + (nq * 2 + n) * 16 + frow;
            const int cb = (s * 64 + kgrp) ^ (((row >> 2) & 1) << 5);
            bv[n][s] = *(const bf16x8v*)(lb + row * 128 + cb);
          }
        #pragma unroll
        for (int j = 0; j < 4; ++j)
          #pragma unroll
          for (int n = 0; n < 2; ++n) {
            acc[mq * 4 + j][nq * 2 + n] = __builtin_amdgcn_mfma_f32_16x16x32_bf16(
                af[j][0], bv[n][0], acc[mq * 4 + j][nq * 2 + n], 0, 0, 0);
            acc[mq * 4 + j][nq * 2 + n] = __builtin_amdgcn_mfma_f32_16x16x32_bf16(
                af[j][1], bv[n][1], acc[mq * 4 + j][nq * 2 + n], 0, 0, 0);
          }
      }
    }
  };

  const int NT = K >> 6;
  stage(0, 0);
  __syncthreads();
  int cur = 0;
  for (int t = 0; t < NT; ++t) {
    if (t + 1 < NT) stage(cur ^ 1, t + 1);
    compute(cur);
    __syncthreads();
    cur ^= 1;
  }

  // ---- epilogue: bias (+gelu), LDS repack, coalesced 16B stores ----
  bf16* cb16 = (bf16*)smem;
  #pragma unroll
  for (int mf = 0; mf < MF; ++mf)
    #pragma unroll
    for (int nf = 0; nf < NF; ++nf) {
      const int col = wcol * 64 + nf * 16 + frow;
      const float bvv = bias[bn * BN + col];
      #pragma unroll
      for (int r = 0; r < 4; ++r) {
        const int row = wrow * RPW + mf * 16 + ((lane >> 4) << 2) + r;
        float v = acc[mf][nf][r] + bvv;
        if (ACT == 1) v = 0.5f * v * (1.0f + erff(v * 0.70710678f));
        cb16[row * PADC + col] = f2b(v);
      }
    }
  __syncthreads();
  constexpr int CPR = BN / 8;              // 16B chunks per row
  #pragma unroll
  for (int j = 0; j < 256 * CPR / 512; ++j) {
    const int idx = tid + j * 512;
    const int row = idx / CPR, c = idx % CPR;
    const ushort8v val = *(const ushort8v*)(cb16 + row * PADC + c * 8);
    *(ushort8v*)(C + ((size_t)bm * 256 + row) * N + bn * BN + c * 8) = val;
  }
}

// ---------------- MFMA attention: one block per (batch, head), 5 waves ----------------
__global__ __launch_bounds__(320) void attn_mfma_kernel(
    const bf16* __restrict__ qkv, bf16* __restrict__ ctx) {
  __shared__ __align__(16) bf16 sK[80][72];
  __shared__ __align__(16) bf16 sVt[64][104];
  __shared__ __align__(16) bf16 sP[5][16][104];
  const int b = blockIdx.x / 12, h = blockIdx.x % 12;
  const int tid = threadIdx.x;
  const int wave = tid >> 6, lane = tid & 63;
  const size_t base = ((size_t)b * 65) * 2304 + (size_t)h * 64;
  const bf16 bzero = f2b(0.f);

  for (int idx = tid; idx < 65 * 16; idx += 320) {
    const int row = idx >> 4, d4 = (idx & 15) * 4;
    const ushort4v kv = *(const ushort4v*)(qkv + base + (size_t)row * 2304 + 768 + d4);
    const ushort4v vv = *(const ushort4v*)(qkv + base + (size_t)row * 2304 + 1536 + d4);
    *(ushort4v*)&sK[row][d4] = kv;
    #pragma unroll
    for (int j = 0; j < 4; ++j) ((unsigned short*)&sVt[d4 + j][row])[0] = vv[j];
  }
  for (int idx = tid; idx < 15 * 16; idx += 320) {
    const int row = 65 + (idx >> 4), d4 = (idx & 15) * 4;
    *(ushort4v*)&sK[row][d4] = ushort4v{0, 0, 0, 0};
  }
  for (int idx = tid; idx < 64 * 31; idx += 320) {
    const int d = idx / 31, c = 65 + (idx % 31);
    sVt[d][c] = bzero;
  }
  __syncthreads();

  const int frow = lane & 15;
  const int koff = (lane >> 4) * 8;
  const int row0 = wave * 16;
  const int qrow = (row0 + frow > 64) ? 64 : (row0 + frow);
  const bf16* qptr = qkv + base + (size_t)qrow * 2304;
  const bf16x8v aq0 = *(const bf16x8v*)(qptr + koff);
  const bf16x8v aq1 = *(const bf16x8v*)(qptr + 32 + koff);

  const f32x4 z4 = {0.f, 0.f, 0.f, 0.f};
  f32x4 sacc[5];
  #pragma unroll
  for (int n = 0; n < 5; ++n) sacc[n] = z4;
  #pragma unroll
  for (int n = 0; n < 5; ++n) {
    const bf16x8v b0 = *(const bf16x8v*)&sK[n * 16 + frow][koff];
    const bf16x8v b1 = *(const bf16x8v*)&sK[n * 16 + frow][32 + koff];
    sacc[n] = __builtin_amdgcn_mfma_f32_16x16x32_bf16(aq0, b0, sacc[n], 0, 0, 0);
    sacc[n] = __builtin_amdgcn_mfma_f32_16x16x32_bf16(aq1, b1, sacc[n], 0, 0, 0);
  }

  #pragma unroll
  for (int r = 0; r < 4; ++r) {
    const int prow = ((lane >> 4) << 2) + r;
    float v[5];
    float mx = -1e30f;
    #pragma unroll
    for (int n = 0; n < 5; ++n) {
      const int col = n * 16 + frow;
      v[n] = (col < 65) ? sacc[n][r] * 0.125f : -1e30f;
      mx = fmaxf(mx, v[n]);
    }
    #pragma unroll
    for (int off = 1; off < 16; off <<= 1) mx = fmaxf(mx, __shfl_xor(mx, off));
    float sum = 0.f;
    #pragma unroll
    for (int n = 0; n < 5; ++n) { v[n] = __expf(v[n] - mx); sum += v[n]; }
    #pragma unroll
    for (int off = 1; off < 16; off <<= 1) sum += __shfl_xor(sum, off);
    const float inv = 1.f / sum;
    #pragma unroll
    for (int n = 0; n < 5; ++n)
      sP[wave][prow][n * 16 + frow] = f2b(v[n] * inv);
    sP[wave][prow][80 + frow] = bzero;
  }

  f32x4 oacc[4];
  #pragma unroll
  for (int n = 0; n < 4; ++n) oacc[n] = z4;
  #pragma unroll
  for (int kk = 0; kk < 3; ++kk) {
    const bf16x8v ap = *(const bf16x8v*)&sP[wave][frow][kk * 32 + koff];
    #pragma unroll
    for (int n = 0; n < 4; ++n) {
      const bf16x8v bv = *(const bf16x8v*)&sVt[n * 16 + frow][kk * 32 + koff];
      oacc[n] = __builtin_amdgcn_mfma_f32_16x16x32_bf16(ap, bv, oacc[n], 0, 0, 0);
    }
  }

  #pragma unroll
  for (int r = 0; r < 4; ++r) {
    const int row = row0 + ((lane >> 4) << 2) + r;
    if (row < 65) {
      bf16* op = ctx + ((size_t)b * 65 + row) * 768 + (size_t)h * 64 + frow;
      #pragma unroll
      for (int n = 0; n < 4; ++n) op[n * 16] = f2b(oacc[n][r]);
    }
  }
}

extern "C" void kernel_launch(void* const* d_in, const int* in_sizes, int n_in,
                              void* d_out, int out_size, void* d_ws, size_t ws_size,
                              hipStream_t stream) {
  (void)in_sizes; (void)n_in; (void)out_size; (void)ws_size;
  const float* inputs     = (const float*)d_in[0];
  const float* randomness = (const float*)d_in[1];
  const int*   perm       = (const int*)d_in[2];
  const float* conv_w     = (const float*)d_in[3];
  const float* conv_b     = (const float*)d_in[4];
  const float* temp_embd  = (const float*)d_in[5];
  const float* spec_embd  = (const float*)d_in[6];
  const float* pos_ln_s   = (const float*)d_in[7];
  const float* pos_ln_b   = (const float*)d_in[8];
  const float* mask_tok   = (const float*)d_in[9];
  const float* agg_tok    = (const float*)d_in[10];
  const float* Wq = (const float*)d_in[11]; const float* bq = (const float*)d_in[12];
  const float* Wk = (const float*)d_in[13]; const float* bk = (const float*)d_in[14];
  const float* Wv = (const float*)d_in[15]; const float* bv = (const float*)d_in[16];
  const float* Wo = (const float*)d_in[17]; const float* bo = (const float*)d_in[18];
  const float* ln1_s = (const float*)d_in[19]; const float* ln1_b = (const float*)d_in[20];
  const float* W1 = (const float*)d_in[21]; const float* b1 = (const float*)d_in[22];
  const float* W2 = (const float*)d_in[23]; const float* b2 = (const float*)d_in[24];
  const float* ln2_s = (const float*)d_in[25]; const float* ln2_b = (const float*)d_in[26];

  char* wsb = (char*)d_ws;
  size_t off = 0;
  auto carve = [&](size_t bytes) { char* p = wsb + off; off = (off + bytes + 255) & ~(size_t)255; return p; };
  bf16* wqkvT = (bf16*)carve((size_t)2 * 2304 * 768 * 2);
  bf16* woT   = (bf16*)carve((size_t)2 * 768 * 768 * 2);
  bf16* w1T   = (bf16*)carve((size_t)2 * 3072 * 768 * 2);
  bf16* w2T   = (bf16*)carve((size_t)2 * 768 * 3072 * 2);
  float* bqkv = (float*)carve((size_t)2 * 2304 * 4);
  bf16* ebuf  = (bf16*)carve((size_t)16640 * 768 * 2);
  bf16* hbuf  = (bf16*)carve((size_t)16640 * 768 * 2);
  bf16* qkvb  = (bf16*)carve((size_t)16640 * 2304 * 2);
  bf16* ctxb  = (bf16*)carve((size_t)16640 * 768 * 2);
  bf16* tmpb  = ebuf;   // e is dead after embed_kernel
  bf16* midb  = qkvb;   // FFN mid [16640,3072] fits in qkv span

  const dim3 blk(256);
  for (int l = 0; l < 2; ++l) {
    transpose_kernel<<<576, blk, 0, stream>>>(Wq + (size_t)l * 768 * 768, wqkvT + (size_t)l * 2304 * 768, 768, 768);
    transpose_kernel<<<576, blk, 0, stream>>>(Wk + (size_t)l * 768 * 768, wqkvT + (size_t)l * 2304 * 768 + 768 * 768, 768, 768);
    transpose_kernel<<<576, blk, 0, stream>>>(Wv + (size_t)l * 768 * 768, wqkvT + (size_t)l * 2304 * 768 + 2 * 768 * 768, 768, 768);
    transpose_kernel<<<576, blk, 0, stream>>>(Wo + (size_t)l * 768 * 768, woT + (size_t)l * 768 * 768, 768, 768);
    transpose_kernel<<<2304, blk, 0, stream>>>(W1 + (size_t)l * 768 * 3072, w1T + (size_t)l * 3072 * 768, 768, 3072);
    transpose_kernel<<<2304, blk, 0, stream>>>(W2 + (size_t)l * 3072 * 768, w2T + (size_t)l * 768 * 3072, 3072, 768);
  }
  biasqkv_kernel<<<18, blk, 0, stream>>>(bq, bk, bv, bqkv);
  patchify_kernel<<<2048, blk, 0, stream>>>(inputs, conv_w, conv_b, ebuf);
  embed_kernel<<<16640, blk, 0, stream>>>(ebuf, randomness, perm, temp_embd, spec_embd,
                                          pos_ln_s, pos_ln_b, mask_tok, agg_tok, hbuf);
  for (int l = 0; l < 2; ++l) {
    gemm256_kernel<4, 0><<<65 * 9, dim3(512), 0, stream>>>(
        (const unsigned short*)hbuf, (const unsigned short*)(wqkvT + (size_t)l * 2304 * 768),
        bqkv + l * 2304, qkvb, 2304, 768, 9);
    attn_mfma_kernel<<<256 * 12, dim3(320), 0, stream>>>(qkvb, ctxb);
    gemm256_kernel<2, 0><<<65 * 6, dim3(512), 0, stream>>>(
        (const unsigned short*)ctxb, (const unsigned short*)(woT + (size_t)l * 768 * 768),
        bo + l * 768, tmpb, 768, 768, 6);
    resln_kernel<0><<<16640, blk, 0, stream>>>(hbuf, tmpb, ln1_s + l * 768, ln1_b + l * 768, hbuf);
    gemm256_kernel<4, 1><<<65 * 12, dim3(512), 0, stream>>>(
        (const unsigned short*)hbuf, (const unsigned short*)(w1T + (size_t)l * 3072 * 768),
        b1 + l * 3072, midb, 3072, 768, 12);
    gemm256_kernel<2, 0><<<65 * 6, dim3(512), 0, stream>>>(
        (const unsigned short*)midb, (const unsigned short*)(w2T + (size_t)l * 768 * 3072),
        b2 + l * 768, tmpb, 768, 3072, 6);
    if (l == 1)
      resln_kernel<1><<<16640, blk, 0, stream>>>(hbuf, tmpb, ln2_s + l * 768, ln2_b + l * 768, d_out);
    else
      resln_kernel<0><<<16640, blk, 0, stream>>>(hbuf, tmpb, ln2_s + l * 768, ln2_b + l * 768, hbuf);
  }
}